// Round 1
// 228.806 us; speedup vs baseline: 1.0024x; 1.0024x over previous
//
#include <hip/hip_runtime.h>

// Morton decode: out[b,c,i,j] = x[b,c,ij], i = odd bits of ij, j = even bits.
// B=8, C=64, L=65536 (S=256), fp32.
//
// R2: one block = TWO Morton-consecutive 64x64 tiles (tmA=2p, tmB=2p+1) =
// one contiguous 32 KB source range. Each thread issues 8 independent 16 B
// loads (64 B contiguous per lane per tile) before any wait -> 2x the
// outstanding-read bytes per wave vs R1, half the wave count, and tile-A
// stores overlap tile-B load returns via progressive vmcnt waits.
// Output tiles are horizontally adjacent (tjB = tjA+1 -> +64 floats), so the
// store pattern per instruction is unchanged: 8 rows x 128 B = 8 full
// cachelines, no write amplification.

typedef float f32x4 __attribute__((ext_vector_type(4)));

__device__ __forceinline__ unsigned compact1by1(unsigned x) {
    // compact the even-position bits of x into the low bits
    x &= 0x55555555u;
    x = (x ^ (x >> 1)) & 0x33333333u;
    x = (x ^ (x >> 2)) & 0x0f0f0f0fu;
    x = (x ^ (x >> 4)) & 0x00ff00ffu;
    return x;
}

__global__ __launch_bounds__(256) void Morton_decode_69312182223578_kernel(
        const float* __restrict__ x, float* __restrict__ out) {
    const unsigned b   = blockIdx.x;
    const unsigned bc  = b >> 3;        // image index 0..511 (B*C)
    const unsigned pr  = b & 7u;        // Morton tile-pair 0..7
    const unsigned tmA = pr << 1;       // even Morton tile index (0,2,..,14)
    // decode morton tile -> (ti, tj): bit0=tj0, bit1=ti0, bit2=tj1, bit3=ti1
    const unsigned tjA = (tmA & 1u) | ((tmA >> 1) & 2u);
    const unsigned tiA = ((tmA >> 1) & 1u) | ((tmA >> 2) & 2u);
    // tmB = tmA+1 flips tj0 (tjA is even) -> same rows, j += 64

    const f32x4* __restrict__ src =
        (const f32x4*)(x + (size_t)bc * 65536u + ((size_t)tmA << 12));
    const unsigned t = threadIdx.x;

    // 8 independent 16 B loads, all outstanding before first use.
    const f32x4 a0 = src[4u * t + 0u];
    const f32x4 a1 = src[4u * t + 1u];
    const f32x4 a2 = src[4u * t + 2u];
    const f32x4 a3 = src[4u * t + 3u];
    const f32x4 b0 = src[1024u + 4u * t + 0u];
    const f32x4 b1 = src[1024u + 4u * t + 1u];
    const f32x4 b2 = src[1024u + 4u * t + 2u];
    const f32x4 b3 = src[1024u + 4u * t + 3u];

    // Quad group g = t: t bits (0..7) = j2,i2,j3,i3,j4,i4,j5,i5
    const unsigned Jh = compact1by1(t);        // j2..j5 (4 bits)
    const unsigned Ih = compact1by1(t >> 1);   // i2..i5 (4 bits)
    const unsigned i0 = tiA * 64u + 4u * Ih;
    const unsigned j0 = tjA * 64u + 4u * Jh;

    float* p = out + (size_t)bc * 65536u + (size_t)i0 * 256u + j0;

    // Tile A: 4 rows. Per store instruction the wave covers 8 rows x 128 B
    // fully-contiguous segments -> full cachelines.
    f32x4 r;
    r = (f32x4){a0.x, a0.y, a1.x, a1.y};
    __builtin_nontemporal_store(r, (f32x4*)(p));
    r = (f32x4){a0.z, a0.w, a1.z, a1.w};
    __builtin_nontemporal_store(r, (f32x4*)(p + 256));
    r = (f32x4){a2.x, a2.y, a3.x, a3.y};
    __builtin_nontemporal_store(r, (f32x4*)(p + 512));
    r = (f32x4){a2.z, a2.w, a3.z, a3.w};
    __builtin_nontemporal_store(r, (f32x4*)(p + 768));

    // Tile B: same rows, +64 floats (adjacent 256 B column band).
    r = (f32x4){b0.x, b0.y, b1.x, b1.y};
    __builtin_nontemporal_store(r, (f32x4*)(p + 64));
    r = (f32x4){b0.z, b0.w, b1.z, b1.w};
    __builtin_nontemporal_store(r, (f32x4*)(p + 320));
    r = (f32x4){b2.x, b2.y, b3.x, b3.y};
    __builtin_nontemporal_store(r, (f32x4*)(p + 576));
    r = (f32x4){b2.z, b2.w, b3.z, b3.w};
    __builtin_nontemporal_store(r, (f32x4*)(p + 832));
}

extern "C" void kernel_launch(void* const* d_in, const int* in_sizes, int n_in,
                              void* d_out, int out_size, void* d_ws, size_t ws_size,
                              hipStream_t stream) {
    const float* x = (const float*)d_in[0];
    float* out = (float*)d_out;
    // 512 images * 8 tile-pairs = 4096 blocks, one pass per block (no loop)
    Morton_decode_69312182223578_kernel<<<4096, 256, 0, stream>>>(x, out);
}